// Round 9
// baseline (336.504 us; speedup 1.0000x reference)
//
#include <hip/hip_runtime.h>

#define N_ 4
#define L_ 1024
#define H_ 8
#define D_ 64

typedef _Float16 f16x8 __attribute__((ext_vector_type(8)));
typedef float f32x4 __attribute__((ext_vector_type(4)));

#define MFMA(A, B, C) __builtin_amdgcn_mfma_f32_16x16x32_f16(A, B, C, 0, 0, 0)

__device__ __forceinline__ ushort f2h(float x) {
    union { _Float16 h; ushort u; } c;
    c.h = (_Float16)x;
    return c.u;
}
__device__ __forceinline__ f16x8 ld8(const ushort* p) {
    return *(const f16x8*)p;
}
__device__ __forceinline__ f16x8 negf(f16x8 a) {
    uint4 u = __builtin_bit_cast(uint4, a);
    u.x ^= 0x80008000u; u.y ^= 0x80008000u; u.z ^= 0x80008000u; u.w ^= 0x80008000u;
    return __builtin_bit_cast(f16x8, u);
}
// load 8 consecutive f32, scale by s, convert to f16x8
__device__ __forceinline__ f16x8 cvt8s(const float* p, float s) {
    float4 a = *(const float4*)p;
    float4 b = *(const float4*)(p + 4);
    union { f16x8 v; _Float16 e[8]; } u;
    u.e[0] = (_Float16)(a.x * s); u.e[1] = (_Float16)(a.y * s);
    u.e[2] = (_Float16)(a.z * s); u.e[3] = (_Float16)(a.w * s);
    u.e[4] = (_Float16)(b.x * s); u.e[5] = (_Float16)(b.y * s);
    u.e[6] = (_Float16)(b.z * s); u.e[7] = (_Float16)(b.w * s);
    return u.v;
}
#define SCQ 0.18033688011112f   // (1/8)*log2(e)
__device__ __forceinline__ f16x8 cvt8(const float* p) { return cvt8s(p, SCQ); }

// ---- convert K: fp32 [n][l][h][d] -> f16 [aid][n][h][l][d], aid in {kr,ki}
__global__ void cvt_k(const float* __restrict__ k_r, const float* __restrict__ k_i,
                      ushort* __restrict__ dst) {
    int gid = blockIdx.x * 256 + threadIdx.x;   // 0..1048575 (x4 elems each)
    int aid = gid >> 19;
    int idx = (gid & 0x7FFFF) << 2;             // flat [n][h][l][d]
    int d  = idx & 63;
    int l  = (idx >> 6) & 1023;
    int hh = (idx >> 16) & 7;
    int n  = idx >> 19;
    const float* src = aid ? k_i : k_r;
    const float4 v = *(const float4*)(src + (((long)n * 1024 + l) * 8 + hh) * 64 + d);
    ushort4 o = make_ushort4(f2h(v.x), f2h(v.y), f2h(v.z), f2h(v.w));
    *(ushort4*)(dst + ((long)aid << 21) + idx) = o;
}

// ---- convert V: fp32 [n][s][h][d] -> f16 transposed [aid][n][h][d][s]
__global__ void cvt_v(const float* __restrict__ vr, const float* __restrict__ vi,
                      ushort* __restrict__ dst) {
    __shared__ ushort t[64][72];
    int bid = blockIdx.x;
    int aid = bid >> 9;
    int b   = bid & 511;
    int s0  = (b & 15) << 6;
    int hh  = (b >> 4) & 7;
    int n   = b >> 7;
    const float* src = aid ? vi : vr;
    int tid = threadIdx.x;
    int r  = tid >> 4;
    int cq = (tid & 15) << 2;
#pragma unroll
    for (int it = 0; it < 4; ++it) {
        int s = s0 + it * 16 + r;
        const float4 v = *(const float4*)(src + (((long)n * 1024 + s) * 8 + hh) * 64 + cq);
        t[it * 16 + r][cq + 0] = f2h(v.x);
        t[it * 16 + r][cq + 1] = f2h(v.y);
        t[it * 16 + r][cq + 2] = f2h(v.z);
        t[it * 16 + r][cq + 3] = f2h(v.w);
    }
    __syncthreads();
#pragma unroll
    for (int it = 0; it < 4; ++it) {
        int dd = it * 16 + r;
        ushort4 o;
        o.x = t[cq + 0][dd]; o.y = t[cq + 1][dd]; o.z = t[cq + 2][dd]; o.w = t[cq + 3][dd];
        *(ushort4*)(dst + ((long)aid << 21) + (((long)n * 8 + hh) * 64 + dd) * 1024 + s0 + cq) = o;
    }
}

// one-parity scores: arg = qr.KA + qix.KB  (qix pre-signed)
#define SCORES1(c, sbi, a0)                                                 \
    do {                                                                    \
        const long soff = (long)((c) * 64 + (sbi) * 16 + col) * 64 + g * 8; \
        f16x8 ka0 = ld8(KA + soff), ka1 = ld8(KA + soff + 32);              \
        f16x8 kb0 = ld8(KB + soff), kb1 = ld8(KB + soff + 32);              \
        a0 = (f32x4){0.f, 0.f, 0.f, 0.f};                                   \
        a0 = MFMA(qr0, ka0, a0); a0 = MFMA(qr1, ka1, a0);                   \
        a0 = MFMA(qx0, kb0, a0); a0 = MFMA(qx1, kb1, a0);                   \
    } while (0)

// both-parity scores (kern_a)
#define SCORES(c, sbi, a0, a1)                                              \
    do {                                                                    \
        const long soff = (long)((c) * 64 + (sbi) * 16 + col) * 64 + g * 8; \
        f16x8 kr0v = ld8(Kr + soff), kr1v = ld8(Kr + soff + 32);            \
        f16x8 ki0v = ld8(Ki + soff), ki1v = ld8(Ki + soff + 32);            \
        a0 = (f32x4){0.f, 0.f, 0.f, 0.f};                                   \
        a0 = MFMA(qr0, kr0v, a0); a0 = MFMA(qr1, kr1v, a0);                 \
        a0 = MFMA(qi0, negf(ki0v), a0); a0 = MFMA(qi1, negf(ki1v), a0);     \
        a1 = (f32x4){0.f, 0.f, 0.f, 0.f};                                   \
        a1 = MFMA(qr0, ki0v, a1); a1 = MFMA(qr1, ki1v, a1);                 \
        a1 = MFMA(qi0, kr0v, a1); a1 = MFMA(qi1, kr1v, a1);                 \
    } while (0)

#define BFLY(x)                                                             \
    x += __shfl_xor(x, 1); x += __shfl_xor(x, 2);                           \
    x += __shfl_xor(x, 4); x += __shfl_xor(x, 8);

// ws element layout (ushort): Kr @0, Ki @1<<21, Vr @2<<21, Vi @3<<21 (16 MB)
// rdbuf (float): byte offset 16 MB, 2*32768 floats.

// ---- single-pass attention for u + rd, PARITY-SPLIT waves ----
// grid 1024 (XCD-swizzled -> (nh, l-tile32)), block 256 = 4 waves:
// wave = (p parity, lsub). Each wave: 16 rows x FULL 1024 s, ONE parity:
//   p=0: P = exp2(qr.kr - qi.ki) (unnorm), d_R, uA = P.Vr, uB = P.Vi
//   p=1: P = exp2(qr.ki + qi.kr),          d_I, uA, uB likewise.
// Epilogue: u_real = oA(0) - oB(1); u_imag = oB(0) + oA(1)  (o = u * rd).
// Main loop barrier-free (wave-private w-LDS); 3 barriers in epilogue.
__launch_bounds__(256, 3)
__global__ void attn_u(const float* __restrict__ qr_g, const float* __restrict__ qi_g,
                       const ushort* __restrict__ ws, float* __restrict__ rdbuf,
                       float* __restrict__ out) {
    __shared__ ushort wtile[4][2][1024];   // [wave][half][16*64] swizzled, 16KB

    const int tid  = threadIdx.x;
    const int lane = tid & 63;
    const int wv   = tid >> 6;
    const int lsub = wv & 1;        // l-subtile
    const int p    = wv >> 1;       // parity: 0=real, 1=imag
    const int col  = lane & 15;
    const int g    = lane >> 4;

    // XCD swizzle: XCD x serves nh in [4x, 4x+4) -> 2MB K+V slice per L2
    const int id = blockIdx.x;
    const int x  = id & 7;
    const int q  = id >> 3;              // 0..127
    const int nh = x * 4 + (q >> 5);
    const int n  = nh >> 3;
    const int h  = nh & 7;
    const int l0 = (q & 31) * 32 + lsub * 16;

    const ushort* Kr = ws + ((long)nh << 16);                 // [1024][64]
    const ushort* Ki = ws + (1l << 21) + ((long)nh << 16);
    const ushort* Vr = ws + (2l << 21) + ((long)nh << 16);    // [64][1024]
    const ushort* Vi = ws + (3l << 21) + ((long)nh << 16);
    const ushort* KA = p ? Ki : Kr;
    const ushort* KB = p ? Kr : Ki;

    // Q fragments (row = col, k = g*8+e, +32); qx pre-signed: -qi for p=0
    const long qg = (((long)n * 1024 + l0 + col) * 8 + h) * 64 + g * 8;
    const float sgn = p ? SCQ : -SCQ;
    const f16x8 qr0 = cvt8(qr_g + qg), qr1 = cvt8(qr_g + qg + 32);
    const f16x8 qx0 = cvt8s(qi_g + qg, sgn), qx1 = cvt8s(qi_g + qg + 32, sgn);

    ushort* wb = &wtile[wv][0][0];

    float ds[4] = {0.f, 0.f, 0.f, 0.f};
    f32x4 uA[4], uB[4];
#pragma unroll
    for (int db = 0; db < 4; ++db) {
        uA[db] = (f32x4){0.f, 0.f, 0.f, 0.f};
        uB[db] = (f32x4){0.f, 0.f, 0.f, 0.f};
    }

    for (int c = 0; c < 16; ++c) {
#pragma unroll
        for (int sb = 0; sb < 4; ++sb) {
            f32x4 a0;
            SCORES1(c, sb, a0);
#pragma unroll
            for (int r = 0; r < 4; ++r) {
                const float wf = exp2f(a0[r]);
                ds[r] += wf;
                const int row = 4 * g + r;
                const int us = (sb * 16 + col) ^ ((row & 7) << 3);
                wb[row * 64 + us] = f2h(wf);
            }
        }
        // A-frag reads (wave-private LDS; in-wave ds order + lgkmcnt suffice)
        const int xr  = ((g ^ (col & 7)) << 3);
        const int xr2 = (((g + 4) ^ (col & 7)) << 3);
        f16x8 w0 = ld8(&wb[col * 64 + xr]);
        f16x8 w1 = ld8(&wb[col * 64 + xr2]);
#pragma unroll
        for (int db = 0; db < 4; ++db) {
            const ushort* vrb = Vr + (long)(db * 16 + col) * 1024 + c * 64 + g * 8;
            f16x8 vr0 = ld8(vrb), vr1 = ld8(vrb + 32);
            const ushort* vib = Vi + (long)(db * 16 + col) * 1024 + c * 64 + g * 8;
            f16x8 vi0 = ld8(vib), vi1 = ld8(vib + 32);
            uA[db] = MFMA(w0, vr0, uA[db]); uA[db] = MFMA(w1, vr1, uA[db]);
            uB[db] = MFMA(w0, vi0, uB[db]); uB[db] = MFMA(w1, vi1, uB[db]);
        }
    }

    BFLY(ds[0]) BFLY(ds[1]) BFLY(ds[2]) BFLY(ds[3])

    float rd[4];
#pragma unroll
    for (int r = 0; r < 4; ++r) rd[r] = 1.f / ds[r];

    if (col == 0) {
#pragma unroll
        for (int r = 0; r < 4; ++r)
            rdbuf[p * 32768 + nh * 1024 + l0 + 4 * g + r] = rd[r];
    }

    // normalized partials
#pragma unroll
    for (int db = 0; db < 4; ++db) {
#pragma unroll
        for (int r = 0; r < 4; ++r) {
            uA[db][r] *= rd[r];
            uB[db][r] *= rd[r];
        }
    }

    // ---- exchange via p=1 waves' dead wtile (contiguous 1KB blocks per db)
    float* cb = (float*)&wtile[2 + lsub][0][0];   // 4KB per lsub-pair
    if (p == 1) {
#pragma unroll
        for (int db = 0; db < 4; ++db) *(f32x4*)&cb[db * 256 + lane * 4] = uB[db];
    }
    __syncthreads();
    f32x4 oR[4];
    if (p == 0) {
#pragma unroll
        for (int db = 0; db < 4; ++db) oR[db] = uA[db] - *(f32x4*)&cb[db * 256 + lane * 4];
    }
    __syncthreads();
    if (p == 1) {
#pragma unroll
        for (int db = 0; db < 4; ++db) *(f32x4*)&cb[db * 256 + lane * 4] = uA[db];
    }
    __syncthreads();

    if (p == 0) {
        const long OFF_UI = 2097152;
#pragma unroll
        for (int db = 0; db < 4; ++db) {
            f32x4 oI = uB[db] + *(f32x4*)&cb[db * 256 + lane * 4];
#pragma unroll
            for (int r = 0; r < 4; ++r) {
                const int l = l0 + 4 * g + r;
                const int d = db * 16 + col;
                const long base = (((long)n * L_ + l) * H_ + h) * D_ + d;
                out[base] = oR[db][r];
                out[OFF_UI + base] = oI[r];
            }
        }
    }
}

// ---- a = 0.125 * sum_h exp2(arg_h) * rd_h ---- recompute QK^T per head
// grid 1024 (XCD-swizzled -> (n, l-tile16, s-quarter)), block 256 = 4 waves;
// wave owns ONE 64-col s-chunk -> acc = 32 VGPR, 16 waves/CU.
__launch_bounds__(256, 4)
__global__ void kern_a(const float* __restrict__ qr_g, const float* __restrict__ qi_g,
                       const ushort* __restrict__ ws, const float* __restrict__ rdbuf,
                       float* __restrict__ out) {
    __shared__ float lrd[8][2][16];   // [h][part][row]

    const int tid  = threadIdx.x;
    const int lane = tid & 63;
    const int wq   = tid >> 6;
    const int col  = lane & 15;
    const int g    = lane >> 4;

    // XCD swizzle: id&7 = XCD; XCD x serves n = x>>1 (K(n) = 2MB per L2)
    const int id  = blockIdx.x;
    const int nid = (id & 7) * 128 + (id >> 3);   // bijective on [0,1024)
    const int n   = nid >> 8;
    const int rem = nid & 255;
    const int l0  = (rem >> 2) << 4;
    const int sq  = rem & 3;
    const int c   = sq * 4 + wq;      // this wave's 64-col chunk

    // preload rd for all heads/rows of this tile: tid -> (h, part, row)
    lrd[tid >> 5][(tid >> 4) & 1][tid & 15] =
        rdbuf[((tid >> 4) & 1) * 32768 + (n * 8 + (tid >> 5)) * 1024 + l0 + (tid & 15)];
    __syncthreads();

    f32x4 aR[4], aI[4];
#pragma unroll
    for (int i = 0; i < 4; ++i) {
        aR[i] = (f32x4){0.f, 0.f, 0.f, 0.f};
        aI[i] = (f32x4){0.f, 0.f, 0.f, 0.f};
    }

    for (int h = 0; h < 8; ++h) {
        const int nh = n * 8 + h;
        const ushort* Kr = ws + ((long)nh << 16);
        const ushort* Ki = ws + (1l << 21) + ((long)nh << 16);
        const long qg = (((long)n * 1024 + l0 + col) * 8 + h) * 64 + g * 8;
        const f16x8 qr0 = cvt8(qr_g + qg), qr1 = cvt8(qr_g + qg + 32);
        const f16x8 qi0 = cvt8(qi_g + qg), qi1 = cvt8(qi_g + qg + 32);
        float rdR[4], rdI[4];
#pragma unroll
        for (int r = 0; r < 4; ++r) {
            rdR[r] = lrd[h][0][4 * g + r];
            rdI[r] = lrd[h][1][4 * g + r];
        }
#pragma unroll
        for (int sb = 0; sb < 4; ++sb) {
            f32x4 a0, a1;
            SCORES(c, sb, a0, a1);
#pragma unroll
            for (int r = 0; r < 4; ++r) {
                aR[sb][r] += exp2f(a0[r]) * rdR[r];
                aI[sb][r] += exp2f(a1[r]) * rdI[r];
            }
        }
    }

    const long OFF_AR = 4194304;
    const long OFF_AI = 8388608;
#pragma unroll
    for (int sb = 0; sb < 4; ++sb) {
#pragma unroll
        for (int r = 0; r < 4; ++r) {
            const int l = l0 + 4 * g + r;
            const int s = c * 64 + sb * 16 + col;
            const long ab = ((long)n * 1024 + l) * 1024 + s;
            out[OFF_AR + ab] = aR[sb][r] * 0.125f;
            out[OFF_AI + ab] = aI[sb][r] * 0.125f;
        }
    }
}

extern "C" void kernel_launch(void* const* d_in, const int* in_sizes, int n_in,
                              void* d_out, int out_size, void* d_ws, size_t ws_size,
                              hipStream_t stream) {
    const float* qr = (const float*)d_in[0];
    const float* qi = (const float*)d_in[1];
    const float* kr = (const float*)d_in[2];
    const float* ki = (const float*)d_in[3];
    const float* vr = (const float*)d_in[4];
    const float* vi = (const float*)d_in[5];
    ushort* ws = (ushort*)d_ws;                              // 16 MB f16 K/V
    float* rdbuf = (float*)((char*)d_ws + (16ull << 20));    // 256 KB @ 16 MB
    float* out = (float*)d_out;

    hipLaunchKernelGGL(cvt_k, dim3(4096), dim3(256), 0, stream, kr, ki, ws);
    hipLaunchKernelGGL(cvt_v, dim3(1024), dim3(256), 0, stream, vr, vi, ws + (2l << 21));
    hipLaunchKernelGGL(attn_u, dim3(1024), dim3(256), 0, stream, qr, qi, ws, rdbuf, out);
    hipLaunchKernelGGL(kern_a, dim3(1024), dim3(256), 0, stream, qr, qi, ws, rdbuf, out);
}

// Round 10
// 159.182 us; speedup vs baseline: 2.1140x; 2.1140x over previous
//
#include <hip/hip_runtime.h>

#define N_ 4
#define L_ 1024
#define H_ 8
#define D_ 64

typedef _Float16 f16x8 __attribute__((ext_vector_type(8)));
typedef float f32x4 __attribute__((ext_vector_type(4)));

#define MFMA(A, B, C) __builtin_amdgcn_mfma_f32_16x16x32_f16(A, B, C, 0, 0, 0)

__device__ __forceinline__ ushort f2h(float x) {
    union { _Float16 h; ushort u; } c;
    c.h = (_Float16)x;
    return c.u;
}
__device__ __forceinline__ f16x8 ld8(const ushort* p) {
    return *(const f16x8*)p;
}
__device__ __forceinline__ f16x8 negf(f16x8 a) {
    uint4 u = __builtin_bit_cast(uint4, a);
    u.x ^= 0x80008000u; u.y ^= 0x80008000u; u.z ^= 0x80008000u; u.w ^= 0x80008000u;
    return __builtin_bit_cast(f16x8, u);
}
// load 8 consecutive f32, scale by s, convert to f16x8
__device__ __forceinline__ f16x8 cvt8s(const float* p, float s) {
    float4 a = *(const float4*)p;
    float4 b = *(const float4*)(p + 4);
    union { f16x8 v; _Float16 e[8]; } u;
    u.e[0] = (_Float16)(a.x * s); u.e[1] = (_Float16)(a.y * s);
    u.e[2] = (_Float16)(a.z * s); u.e[3] = (_Float16)(a.w * s);
    u.e[4] = (_Float16)(b.x * s); u.e[5] = (_Float16)(b.y * s);
    u.e[6] = (_Float16)(b.z * s); u.e[7] = (_Float16)(b.w * s);
    return u.v;
}
#define SCQ 0.18033688011112f   // (1/8)*log2(e)
__device__ __forceinline__ f16x8 cvt8(const float* p) { return cvt8s(p, SCQ); }

// async global -> LDS, 16B per lane, wave-uniform LDS base + lane*16
__device__ __forceinline__ void gl_lds16(const ushort* g, ushort* l) {
    __builtin_amdgcn_global_load_lds(
        (const __attribute__((address_space(1))) unsigned int*)g,
        (__attribute__((address_space(3))) unsigned int*)l, 16, 0, 0);
}

// ---- convert K: fp32 [n][l][h][d] -> f16 [aid][n][h][l][d], aid in {kr,ki}
__global__ void cvt_k(const float* __restrict__ k_r, const float* __restrict__ k_i,
                      ushort* __restrict__ dst) {
    int gid = blockIdx.x * 256 + threadIdx.x;   // 0..1048575 (x4 elems each)
    int aid = gid >> 19;
    int idx = (gid & 0x7FFFF) << 2;             // flat [n][h][l][d]
    int d  = idx & 63;
    int l  = (idx >> 6) & 1023;
    int hh = (idx >> 16) & 7;
    int n  = idx >> 19;
    const float* src = aid ? k_i : k_r;
    const float4 v = *(const float4*)(src + (((long)n * 1024 + l) * 8 + hh) * 64 + d);
    ushort4 o = make_ushort4(f2h(v.x), f2h(v.y), f2h(v.z), f2h(v.w));
    *(ushort4*)(dst + ((long)aid << 21) + idx) = o;
}

// ---- convert V: fp32 [n][s][h][d] -> f16 transposed [aid][n][h][d][s]
__global__ void cvt_v(const float* __restrict__ vr, const float* __restrict__ vi,
                      ushort* __restrict__ dst) {
    __shared__ ushort t[64][72];
    int bid = blockIdx.x;
    int aid = bid >> 9;
    int b   = bid & 511;
    int s0  = (b & 15) << 6;
    int hh  = (b >> 4) & 7;
    int n   = b >> 7;
    const float* src = aid ? vi : vr;
    int tid = threadIdx.x;
    int r  = tid >> 4;
    int cq = (tid & 15) << 2;
#pragma unroll
    for (int it = 0; it < 4; ++it) {
        int s = s0 + it * 16 + r;
        const float4 v = *(const float4*)(src + (((long)n * 1024 + s) * 8 + hh) * 64 + cq);
        t[it * 16 + r][cq + 0] = f2h(v.x);
        t[it * 16 + r][cq + 1] = f2h(v.y);
        t[it * 16 + r][cq + 2] = f2h(v.z);
        t[it * 16 + r][cq + 3] = f2h(v.w);
    }
    __syncthreads();
#pragma unroll
    for (int it = 0; it < 4; ++it) {
        int dd = it * 16 + r;
        ushort4 o;
        o.x = t[cq + 0][dd]; o.y = t[cq + 1][dd]; o.z = t[cq + 2][dd]; o.w = t[cq + 3][dd];
        *(ushort4*)(dst + ((long)aid << 21) + (((long)n * 8 + hh) * 64 + dd) * 1024 + s0 + cq) = o;
    }
}

// both-parity scores from GLOBAL K (kern_a only)
#define SCORES(c, sbi, a0, a1)                                              \
    do {                                                                    \
        const long soff = (long)((c) * 64 + (sbi) * 16 + col) * 64 + g * 8; \
        f16x8 kr0v = ld8(Kr + soff), kr1v = ld8(Kr + soff + 32);            \
        f16x8 ki0v = ld8(Ki + soff), ki1v = ld8(Ki + soff + 32);            \
        a0 = (f32x4){0.f, 0.f, 0.f, 0.f};                                   \
        a0 = MFMA(qr0, kr0v, a0); a0 = MFMA(qr1, kr1v, a0);                 \
        a0 = MFMA(qi0, negf(ki0v), a0); a0 = MFMA(qi1, negf(ki1v), a0);     \
        a1 = (f32x4){0.f, 0.f, 0.f, 0.f};                                   \
        a1 = MFMA(qr0, ki0v, a1); a1 = MFMA(qr1, ki1v, a1);                 \
        a1 = MFMA(qi0, kr0v, a1); a1 = MFMA(qi1, kr1v, a1);                 \
    } while (0)

#define BFLY(x)                                                             \
    x += __shfl_xor(x, 1); x += __shfl_xor(x, 2);                           \
    x += __shfl_xor(x, 4); x += __shfl_xor(x, 8);

// ws element layout (ushort): Kr @0, Ki @1<<21, Vr @2<<21, Vi @3<<21 (16 MB)
// rdbuf (float): byte offset 16 MB, 2*32768 floats.

// ---- flash-style single-pass attention for u + rd ----
// grid 256 (XCD-swizzled -> (nh, l-tile128)), block 512 = 8 waves (same nh),
// wave owns 16 rows. s-chunks of 32, K/V staged to LDS via global_load_lds
// (both-sides XOR swizzle), double-buffered, 2-phase pipeline. Per-wave
// full-parity accumulation (r6 math): u_real = uRR*rdR - uII*rdI, etc.
__launch_bounds__(512, 2)
__global__ void attn_u(const float* __restrict__ qr_g, const float* __restrict__ qi_g,
                       const ushort* __restrict__ ws, float* __restrict__ rdbuf,
                       float* __restrict__ out) {
    __shared__ ushort stgK[2][2][32][64];   // [buf][part][s][d]     16KB
    __shared__ ushort stgV[2][2][64][32];   // [buf][part][d][s]     16KB
    __shared__ ushort wtl[8][2][16][32];    // [wave][part][l][s]    16KB

    const int tid  = threadIdx.x;
    const int lane = tid & 63;
    const int wv   = tid >> 6;
    const int col  = lane & 15;
    const int g    = lane >> 4;

    // XCD swizzle: XCD x serves nh in [4x,4x+4) -> 2MB K+V slice per L2
    const int id = blockIdx.x;
    const int x  = id & 7;
    const int j  = id >> 3;              // 0..31
    const int nh = x * 4 + (j >> 3);
    const int n  = nh >> 3;
    const int h  = nh & 7;
    const int l0 = (j & 7) * 128 + wv * 16;

    const ushort* Kr = ws + ((long)nh << 16);                 // [1024][64]
    const ushort* Ki = ws + (1l << 21) + ((long)nh << 16);
    const ushort* Vr = ws + (2l << 21) + ((long)nh << 16);    // [64][1024]
    const ushort* Vi = ws + (3l << 21) + ((long)nh << 16);

    // Q fragments (row = col, k = g*8+e, +32), qn = -qi (all scaled SCQ)
    const long qg = (((long)n * 1024 + l0 + col) * 8 + h) * 64 + g * 8;
    const f16x8 qr0 = cvt8(qr_g + qg), qr1 = cvt8(qr_g + qg + 32);
    const f16x8 qi0 = cvt8(qi_g + qg), qi1 = cvt8(qi_g + qg + 32);
    const f16x8 qn0 = negf(qi0), qn1 = negf(qi1);

    // staging roles (fixed per wave): waves 0-3 part0, waves 4-7 part1
    const int sp  = wv >> 2;                       // part this wave stages
    const int krow = (wv & 3) * 8 + (lane >> 3);   // K row (of 32)
    const int kbs  = ((lane & 7) ^ (krow & 7)) * 8;
    const int vrow = (wv & 3) * 16 + (lane >> 2);  // V row (of 64)
    const int vbs  = ((lane & 3) ^ (vrow & 3)) * 8;
    const ushort* Kst = sp ? Ki : Kr;
    const ushort* Vst = sp ? Vi : Vr;

    float dRs[4] = {0.f, 0.f, 0.f, 0.f};
    float dIs[4] = {0.f, 0.f, 0.f, 0.f};
    f32x4 uRR[4], uII[4], uRI[4], uIR[4];
#pragma unroll
    for (int db = 0; db < 4; ++db) {
        uRR[db] = (f32x4){0.f, 0.f, 0.f, 0.f};
        uII[db] = (f32x4){0.f, 0.f, 0.f, 0.f};
        uRI[db] = (f32x4){0.f, 0.f, 0.f, 0.f};
        uIR[db] = (f32x4){0.f, 0.f, 0.f, 0.f};
    }

    // read-side swizzled block offsets (lane-constant)
    const int kx  = (g ^ (col & 7)) * 8;         // K blocks (8/row)
    const int kx2 = ((g + 4) ^ (col & 7)) * 8;
    const int vx  = (g ^ (col & 3)) * 8;         // V & w blocks (4/row)

#define STAGE(buf, cc)                                                       \
    do {                                                                     \
        gl_lds16(Kst + (long)((cc) * 32 + krow) * 64 + kbs,                  \
                 &stgK[buf][sp][(wv & 3) * 8][0]);                           \
        gl_lds16(Vst + (long)vrow * 1024 + (cc) * 32 + vbs,                  \
                 &stgV[buf][sp][(wv & 3) * 16][0]);                          \
    } while (0)

    STAGE(0, 0);
    __syncthreads();

    for (int cc = 0; cc < 32; ++cc) {
        const int buf = cc & 1;
        if (cc < 31) STAGE(buf ^ 1, cc + 1);

        // ---- QK^T + exp2 -> w-tile (wave-private) ----
#pragma unroll
        for (int sb = 0; sb < 2; ++sb) {
            const int row = sb * 16 + col;
            f16x8 kr0 = ld8(&stgK[buf][0][row][kx]);
            f16x8 kr1 = ld8(&stgK[buf][0][row][kx2]);
            f16x8 ki0 = ld8(&stgK[buf][1][row][kx]);
            f16x8 ki1 = ld8(&stgK[buf][1][row][kx2]);
            f32x4 a0 = (f32x4){0.f, 0.f, 0.f, 0.f};
            a0 = MFMA(qr0, kr0, a0); a0 = MFMA(qr1, kr1, a0);
            a0 = MFMA(qn0, ki0, a0); a0 = MFMA(qn1, ki1, a0);
            f32x4 a1 = (f32x4){0.f, 0.f, 0.f, 0.f};
            a1 = MFMA(qr0, ki0, a1); a1 = MFMA(qr1, ki1, a1);
            a1 = MFMA(qi0, kr0, a1); a1 = MFMA(qi1, kr1, a1);
#pragma unroll
            for (int r = 0; r < 4; ++r) {
                const float wf = exp2f(a0[r]);
                const float vf = exp2f(a1[r]);
                dRs[r] += wf;
                dIs[r] += vf;
                const int l = 4 * g + r;
                const int scol = sb * 16 + col;
                const int us = l * 32 + (((scol >> 3) ^ (l & 3)) << 3) + (scol & 7);
                (&wtl[wv][0][0][0])[us] = f2h(wf);
                (&wtl[wv][1][0][0])[us] = f2h(vf);
            }
        }

        // ---- PV (k=32) ----
        f16x8 wr0 = ld8(&wtl[wv][0][col][vx]);
        f16x8 wi0 = ld8(&wtl[wv][1][col][vx]);
#pragma unroll
        for (int db = 0; db < 4; ++db) {
            const int row = db * 16 + col;
            f16x8 vr0 = ld8(&stgV[buf][0][row][vx]);
            f16x8 vi0 = ld8(&stgV[buf][1][row][vx]);
            uRR[db] = MFMA(wr0, vr0, uRR[db]);
            uII[db] = MFMA(wi0, vi0, uII[db]);
            uRI[db] = MFMA(wr0, vi0, uRI[db]);
            uIR[db] = MFMA(wi0, vr0, uIR[db]);
        }

        __syncthreads();   // staged buf^1 complete (vmcnt0) + all done with buf
    }

    BFLY(dRs[0]) BFLY(dRs[1]) BFLY(dRs[2]) BFLY(dRs[3])
    BFLY(dIs[0]) BFLY(dIs[1]) BFLY(dIs[2]) BFLY(dIs[3])

    float rdR[4], rdI[4];
#pragma unroll
    for (int r = 0; r < 4; ++r) { rdR[r] = 1.f / dRs[r]; rdI[r] = 1.f / dIs[r]; }

    if (col == 0) {
#pragma unroll
        for (int r = 0; r < 4; ++r) {
            rdbuf[nh * 1024 + l0 + 4 * g + r] = rdR[r];
            rdbuf[32768 + nh * 1024 + l0 + 4 * g + r] = rdI[r];
        }
    }

    const long OFF_UI = 2097152;
#pragma unroll
    for (int db = 0; db < 4; ++db) {
#pragma unroll
        for (int r = 0; r < 4; ++r) {
            const int l = l0 + 4 * g + r;
            const int d = db * 16 + col;
            const long base = (((long)n * L_ + l) * H_ + h) * D_ + d;
            out[base] = uRR[db][r] * rdR[r] - uII[db][r] * rdI[r];
            out[OFF_UI + base] = uRI[db][r] * rdR[r] + uIR[db][r] * rdI[r];
        }
    }
#undef STAGE
}

// ---- a = 0.125 * sum_h exp2(arg_h) * rd_h ---- recompute QK^T per head
// grid 1024 (XCD-swizzled -> (n, l-tile16, s-quarter)), block 256 = 4 waves;
// wave owns ONE 64-col s-chunk -> acc = 32 VGPR, 16 waves/CU.
__launch_bounds__(256, 4)
__global__ void kern_a(const float* __restrict__ qr_g, const float* __restrict__ qi_g,
                       const ushort* __restrict__ ws, const float* __restrict__ rdbuf,
                       float* __restrict__ out) {
    __shared__ float lrd[8][2][16];   // [h][part][row]

    const int tid  = threadIdx.x;
    const int lane = tid & 63;
    const int wq   = tid >> 6;
    const int col  = lane & 15;
    const int g    = lane >> 4;

    // XCD swizzle: id&7 = XCD; XCD x serves n = x>>1 (K(n) = 2MB per L2)
    const int id  = blockIdx.x;
    const int nid = (id & 7) * 128 + (id >> 3);   // bijective on [0,1024)
    const int n   = nid >> 8;
    const int rem = nid & 255;
    const int l0  = (rem >> 2) << 4;
    const int sq  = rem & 3;
    const int c   = sq * 4 + wq;      // this wave's 64-col chunk

    // preload rd for all heads/rows of this tile: tid -> (h, part, row)
    lrd[tid >> 5][(tid >> 4) & 1][tid & 15] =
        rdbuf[((tid >> 4) & 1) * 32768 + (n * 8 + (tid >> 5)) * 1024 + l0 + (tid & 15)];
    __syncthreads();

    f32x4 aR[4], aI[4];
#pragma unroll
    for (int i = 0; i < 4; ++i) {
        aR[i] = (f32x4){0.f, 0.f, 0.f, 0.f};
        aI[i] = (f32x4){0.f, 0.f, 0.f, 0.f};
    }

    for (int h = 0; h < 8; ++h) {
        const int nh = n * 8 + h;
        const ushort* Kr = ws + ((long)nh << 16);
        const ushort* Ki = ws + (1l << 21) + ((long)nh << 16);
        const long qg = (((long)n * 1024 + l0 + col) * 8 + h) * 64 + g * 8;
        const f16x8 qr0 = cvt8(qr_g + qg), qr1 = cvt8(qr_g + qg + 32);
        const f16x8 qi0 = cvt8(qi_g + qg), qi1 = cvt8(qi_g + qg + 32);
        float rdR[4], rdI[4];
#pragma unroll
        for (int r = 0; r < 4; ++r) {
            rdR[r] = lrd[h][0][4 * g + r];
            rdI[r] = lrd[h][1][4 * g + r];
        }
#pragma unroll
        for (int sb = 0; sb < 4; ++sb) {
            f32x4 a0, a1;
            SCORES(c, sb, a0, a1);
#pragma unroll
            for (int r = 0; r < 4; ++r) {
                aR[sb][r] += exp2f(a0[r]) * rdR[r];
                aI[sb][r] += exp2f(a1[r]) * rdI[r];
            }
        }
    }

    const long OFF_AR = 4194304;
    const long OFF_AI = 8388608;
#pragma unroll
    for (int sb = 0; sb < 4; ++sb) {
#pragma unroll
        for (int r = 0; r < 4; ++r) {
            const int l = l0 + 4 * g + r;
            const int s = c * 64 + sb * 16 + col;
            const long ab = ((long)n * 1024 + l) * 1024 + s;
            out[OFF_AR + ab] = aR[sb][r] * 0.125f;
            out[OFF_AI + ab] = aI[sb][r] * 0.125f;
        }
    }
}

extern "C" void kernel_launch(void* const* d_in, const int* in_sizes, int n_in,
                              void* d_out, int out_size, void* d_ws, size_t ws_size,
                              hipStream_t stream) {
    const float* qr = (const float*)d_in[0];
    const float* qi = (const float*)d_in[1];
    const float* kr = (const float*)d_in[2];
    const float* ki = (const float*)d_in[3];
    const float* vr = (const float*)d_in[4];
    const float* vi = (const float*)d_in[5];
    ushort* ws = (ushort*)d_ws;                              // 16 MB f16 K/V
    float* rdbuf = (float*)((char*)d_ws + (16ull << 20));    // 256 KB @ 16 MB
    float* out = (float*)d_out;

    hipLaunchKernelGGL(cvt_k, dim3(4096), dim3(256), 0, stream, kr, ki, ws);
    hipLaunchKernelGGL(cvt_v, dim3(1024), dim3(256), 0, stream, vr, vi, ws + (2l << 21));
    hipLaunchKernelGGL(attn_u, dim3(256), dim3(512), 0, stream, qr, qi, ws, rdbuf, out);
    hipLaunchKernelGGL(kern_a, dim3(1024), dim3(256), 0, stream, qr, qi, ws, rdbuf, out);
}

// Round 11
// 111.912 us; speedup vs baseline: 3.0069x; 1.4224x over previous
//
#include <hip/hip_runtime.h>

#define N_ 4
#define L_ 1024
#define H_ 8
#define D_ 64

typedef _Float16 f16x8 __attribute__((ext_vector_type(8)));
typedef float f32x4 __attribute__((ext_vector_type(4)));

#define MFMA(A, B, C) __builtin_amdgcn_mfma_f32_16x16x32_f16(A, B, C, 0, 0, 0)

__device__ __forceinline__ ushort f2h(float x) {
    union { _Float16 h; ushort u; } c;
    c.h = (_Float16)x;
    return c.u;
}
__device__ __forceinline__ f16x8 ld8(const ushort* p) {
    return *(const f16x8*)p;
}
__device__ __forceinline__ f16x8 negf(f16x8 a) {
    uint4 u = __builtin_bit_cast(uint4, a);
    u.x ^= 0x80008000u; u.y ^= 0x80008000u; u.z ^= 0x80008000u; u.w ^= 0x80008000u;
    return __builtin_bit_cast(f16x8, u);
}
// load 8 consecutive f32, scale by s, convert to f16x8
__device__ __forceinline__ f16x8 cvt8s(const float* p, float s) {
    float4 a = *(const float4*)p;
    float4 b = *(const float4*)(p + 4);
    union { f16x8 v; _Float16 e[8]; } u;
    u.e[0] = (_Float16)(a.x * s); u.e[1] = (_Float16)(a.y * s);
    u.e[2] = (_Float16)(a.z * s); u.e[3] = (_Float16)(a.w * s);
    u.e[4] = (_Float16)(b.x * s); u.e[5] = (_Float16)(b.y * s);
    u.e[6] = (_Float16)(b.z * s); u.e[7] = (_Float16)(b.w * s);
    return u.v;
}
#define SCQ 0.18033688011112f   // (1/8)*log2(e)
__device__ __forceinline__ f16x8 cvt8(const float* p) { return cvt8s(p, SCQ); }

// async global -> LDS, 16B per lane, wave-uniform LDS base + lane*16
__device__ __forceinline__ void gl_lds16(const ushort* g, ushort* l) {
    __builtin_amdgcn_global_load_lds(
        (const __attribute__((address_space(1))) unsigned int*)g,
        (__attribute__((address_space(3))) unsigned int*)l, 16, 0, 0);
}

// ---- convert K: fp32 [n][l][h][d] -> f16 [aid][n][h][l][d], aid in {kr,ki}
__global__ void cvt_k(const float* __restrict__ k_r, const float* __restrict__ k_i,
                      ushort* __restrict__ dst) {
    int gid = blockIdx.x * 256 + threadIdx.x;   // 0..1048575 (x4 elems each)
    int aid = gid >> 19;
    int idx = (gid & 0x7FFFF) << 2;             // flat [n][h][l][d]
    int d  = idx & 63;
    int l  = (idx >> 6) & 1023;
    int hh = (idx >> 16) & 7;
    int n  = idx >> 19;
    const float* src = aid ? k_i : k_r;
    const float4 v = *(const float4*)(src + (((long)n * 1024 + l) * 8 + hh) * 64 + d);
    ushort4 o = make_ushort4(f2h(v.x), f2h(v.y), f2h(v.z), f2h(v.w));
    *(ushort4*)(dst + ((long)aid << 21) + idx) = o;
}

// ---- convert V: fp32 [n][s][h][d] -> f16 transposed [aid][n][h][d][s]
__global__ void cvt_v(const float* __restrict__ vr, const float* __restrict__ vi,
                      ushort* __restrict__ dst) {
    __shared__ ushort t[64][72];
    int bid = blockIdx.x;
    int aid = bid >> 9;
    int b   = bid & 511;
    int s0  = (b & 15) << 6;
    int hh  = (b >> 4) & 7;
    int n   = b >> 7;
    const float* src = aid ? vi : vr;
    int tid = threadIdx.x;
    int r  = tid >> 4;
    int cq = (tid & 15) << 2;
#pragma unroll
    for (int it = 0; it < 4; ++it) {
        int s = s0 + it * 16 + r;
        const float4 v = *(const float4*)(src + (((long)n * 1024 + s) * 8 + hh) * 64 + cq);
        t[it * 16 + r][cq + 0] = f2h(v.x);
        t[it * 16 + r][cq + 1] = f2h(v.y);
        t[it * 16 + r][cq + 2] = f2h(v.z);
        t[it * 16 + r][cq + 3] = f2h(v.w);
    }
    __syncthreads();
#pragma unroll
    for (int it = 0; it < 4; ++it) {
        int dd = it * 16 + r;
        ushort4 o;
        o.x = t[cq + 0][dd]; o.y = t[cq + 1][dd]; o.z = t[cq + 2][dd]; o.w = t[cq + 3][dd];
        *(ushort4*)(dst + ((long)aid << 21) + (((long)n * 8 + hh) * 64 + dd) * 1024 + s0 + cq) = o;
    }
}

#define BFLY(x)                                                             \
    x += __shfl_xor(x, 1); x += __shfl_xor(x, 2);                           \
    x += __shfl_xor(x, 4); x += __shfl_xor(x, 8);

// ws element layout (ushort): Kr @0, Ki @1<<21, Vr @2<<21, Vi @3<<21 (16 MB)
// rdbuf (float): byte offset 16 MB, 2*32768 floats.

// ---- flash-style single-pass attention for u + rd ----
// grid 256 (XCD-swizzled -> (nh, l-tile128)), block 512 = 8 waves (same nh),
// wave owns 16 rows. s-chunks of 32, K/V staged to LDS via global_load_lds
// (both-sides XOR swizzle), double-buffered, 2-phase pipeline. Per-wave
// full-parity accumulation (r6 math): u_real = uRR*rdR - uII*rdI, etc.
__launch_bounds__(512, 2)
__global__ void attn_u(const float* __restrict__ qr_g, const float* __restrict__ qi_g,
                       const ushort* __restrict__ ws, float* __restrict__ rdbuf,
                       float* __restrict__ out) {
    __shared__ ushort stgK[2][2][32][64];   // [buf][part][s][d]     16KB
    __shared__ ushort stgV[2][2][64][32];   // [buf][part][d][s]     16KB
    __shared__ ushort wtl[8][2][16][32];    // [wave][part][l][s]    16KB

    const int tid  = threadIdx.x;
    const int lane = tid & 63;
    const int wv   = tid >> 6;
    const int col  = lane & 15;
    const int g    = lane >> 4;

    // XCD swizzle: XCD x serves nh in [4x,4x+4) -> 2MB K+V slice per L2
    const int id = blockIdx.x;
    const int x  = id & 7;
    const int j  = id >> 3;              // 0..31
    const int nh = x * 4 + (j >> 3);
    const int n  = nh >> 3;
    const int h  = nh & 7;
    const int l0 = (j & 7) * 128 + wv * 16;

    const ushort* Kr = ws + ((long)nh << 16);                 // [1024][64]
    const ushort* Ki = ws + (1l << 21) + ((long)nh << 16);
    const ushort* Vr = ws + (2l << 21) + ((long)nh << 16);    // [64][1024]
    const ushort* Vi = ws + (3l << 21) + ((long)nh << 16);

    // Q fragments (row = col, k = g*8+e, +32), qn = -qi (all scaled SCQ)
    const long qg = (((long)n * 1024 + l0 + col) * 8 + h) * 64 + g * 8;
    const f16x8 qr0 = cvt8(qr_g + qg), qr1 = cvt8(qr_g + qg + 32);
    const f16x8 qi0 = cvt8(qi_g + qg), qi1 = cvt8(qi_g + qg + 32);
    const f16x8 qn0 = negf(qi0), qn1 = negf(qi1);

    // staging roles (fixed per wave): waves 0-3 part0, waves 4-7 part1
    const int sp  = wv >> 2;                       // part this wave stages
    const int krow = (wv & 3) * 8 + (lane >> 3);   // K row (of 32)
    const int kbs  = ((lane & 7) ^ (krow & 7)) * 8;
    const int vrow = (wv & 3) * 16 + (lane >> 2);  // V row (of 64)
    const int vbs  = ((lane & 3) ^ (vrow & 3)) * 8;
    const ushort* Kst = sp ? Ki : Kr;
    const ushort* Vst = sp ? Vi : Vr;

    float dRs[4] = {0.f, 0.f, 0.f, 0.f};
    float dIs[4] = {0.f, 0.f, 0.f, 0.f};
    f32x4 uRR[4], uII[4], uRI[4], uIR[4];
#pragma unroll
    for (int db = 0; db < 4; ++db) {
        uRR[db] = (f32x4){0.f, 0.f, 0.f, 0.f};
        uII[db] = (f32x4){0.f, 0.f, 0.f, 0.f};
        uRI[db] = (f32x4){0.f, 0.f, 0.f, 0.f};
        uIR[db] = (f32x4){0.f, 0.f, 0.f, 0.f};
    }

    // read-side swizzled block offsets (lane-constant)
    const int kx  = (g ^ (col & 7)) * 8;         // K blocks (8/row)
    const int kx2 = ((g + 4) ^ (col & 7)) * 8;
    const int vx  = (g ^ (col & 3)) * 8;         // V & w blocks (4/row)

#define STAGE(buf, cc)                                                       \
    do {                                                                     \
        gl_lds16(Kst + (long)((cc) * 32 + krow) * 64 + kbs,                  \
                 &stgK[buf][sp][(wv & 3) * 8][0]);                           \
        gl_lds16(Vst + (long)vrow * 1024 + (cc) * 32 + vbs,                  \
                 &stgV[buf][sp][(wv & 3) * 16][0]);                          \
    } while (0)

    STAGE(0, 0);
    __syncthreads();

    for (int cc = 0; cc < 32; ++cc) {
        const int buf = cc & 1;
        if (cc < 31) STAGE(buf ^ 1, cc + 1);

        // ---- QK^T + exp2 -> w-tile (wave-private) ----
#pragma unroll
        for (int sb = 0; sb < 2; ++sb) {
            const int row = sb * 16 + col;
            f16x8 kr0 = ld8(&stgK[buf][0][row][kx]);
            f16x8 kr1 = ld8(&stgK[buf][0][row][kx2]);
            f16x8 ki0 = ld8(&stgK[buf][1][row][kx]);
            f16x8 ki1 = ld8(&stgK[buf][1][row][kx2]);
            f32x4 a0 = (f32x4){0.f, 0.f, 0.f, 0.f};
            a0 = MFMA(qr0, kr0, a0); a0 = MFMA(qr1, kr1, a0);
            a0 = MFMA(qn0, ki0, a0); a0 = MFMA(qn1, ki1, a0);
            f32x4 a1 = (f32x4){0.f, 0.f, 0.f, 0.f};
            a1 = MFMA(qr0, ki0, a1); a1 = MFMA(qr1, ki1, a1);
            a1 = MFMA(qi0, kr0, a1); a1 = MFMA(qi1, kr1, a1);
#pragma unroll
            for (int r = 0; r < 4; ++r) {
                const float wf = exp2f(a0[r]);
                const float vf = exp2f(a1[r]);
                dRs[r] += wf;
                dIs[r] += vf;
                const int l = 4 * g + r;
                const int scol = sb * 16 + col;
                const int us = l * 32 + (((scol >> 3) ^ (l & 3)) << 3) + (scol & 7);
                (&wtl[wv][0][0][0])[us] = f2h(wf);
                (&wtl[wv][1][0][0])[us] = f2h(vf);
            }
        }

        // ---- PV (k=32) ----
        f16x8 wr0 = ld8(&wtl[wv][0][col][vx]);
        f16x8 wi0 = ld8(&wtl[wv][1][col][vx]);
#pragma unroll
        for (int db = 0; db < 4; ++db) {
            const int row = db * 16 + col;
            f16x8 vr0 = ld8(&stgV[buf][0][row][vx]);
            f16x8 vi0 = ld8(&stgV[buf][1][row][vx]);
            uRR[db] = MFMA(wr0, vr0, uRR[db]);
            uII[db] = MFMA(wi0, vi0, uII[db]);
            uRI[db] = MFMA(wr0, vi0, uRI[db]);
            uIR[db] = MFMA(wi0, vr0, uIR[db]);
        }

        __syncthreads();   // staged buf^1 complete (vmcnt0) + all done with buf
    }

    BFLY(dRs[0]) BFLY(dRs[1]) BFLY(dRs[2]) BFLY(dRs[3])
    BFLY(dIs[0]) BFLY(dIs[1]) BFLY(dIs[2]) BFLY(dIs[3])

    float rdR[4], rdI[4];
#pragma unroll
    for (int r = 0; r < 4; ++r) { rdR[r] = 1.f / dRs[r]; rdI[r] = 1.f / dIs[r]; }

    if (col == 0) {
#pragma unroll
        for (int r = 0; r < 4; ++r) {
            rdbuf[nh * 1024 + l0 + 4 * g + r] = rdR[r];
            rdbuf[32768 + nh * 1024 + l0 + 4 * g + r] = rdI[r];
        }
    }

    const long OFF_UI = 2097152;
#pragma unroll
    for (int db = 0; db < 4; ++db) {
#pragma unroll
        for (int r = 0; r < 4; ++r) {
            const int l = l0 + 4 * g + r;
            const int d = db * 16 + col;
            const long base = (((long)n * L_ + l) * H_ + h) * D_ + d;
            out[base] = uRR[db][r] * rdR[r] - uII[db][r] * rdI[r];
            out[OFF_UI + base] = uRI[db][r] * rdR[r] + uIR[db][r] * rdI[r];
        }
    }
#undef STAGE
}

// ---- a = 0.125 * sum_h exp2(arg_h) * rd_h ---- LDS-staged K recompute
// grid 1024 (XCD-swizzled -> (n, l-tile64, s-chunk64)), block 256 = 4 waves,
// wave owns 16 l-rows x full 64-s chunk. h-loop with double-buffered LDS K
// staging (global_load_lds, both-sides XOR swizzle), in-register h-sum.
__launch_bounds__(256, 4)
__global__ void kern_a(const float* __restrict__ qr_g, const float* __restrict__ qi_g,
                       const ushort* __restrict__ ws, const float* __restrict__ rdbuf,
                       float* __restrict__ out) {
    __shared__ ushort stgK[2][2][64][64];   // [buf][part][s][d]  32KB
    __shared__ float lrd[8][2][64];         // [h][part][row]      4KB

    const int tid  = threadIdx.x;
    const int lane = tid & 63;
    const int wv   = tid >> 6;
    const int col  = lane & 15;
    const int g    = lane >> 4;

    // XCD swizzle: id&7 = XCD x; n = x>>1 -> K(n)=4MB resident per L2 pair
    const int id  = blockIdx.x;
    const int x   = id & 7;
    const int q   = id >> 3;             // 0..127
    const int n   = x >> 1;
    const int idx = (x & 1) * 128 + q;   // 0..255 within n
    const int lt0 = (idx >> 4) * 64;     // l-tile base
    const int sc  = idx & 15;            // s-chunk (64 cols)
    const int l0  = lt0 + wv * 16;       // wave's row base

    const ushort* KrB = ws + ((long)(n * 8) << 16);             // head 0
    const ushort* KiB = ws + (1l << 21) + ((long)(n * 8) << 16);

    // preload rd for all 8 heads x 64 rows
#pragma unroll
    for (int i = 0; i < 4; ++i) {
        const int t = i * 256 + tid;
        (&lrd[0][0][0])[t] =
            rdbuf[((t >> 6) & 1) * 32768 + (n * 8 + (t >> 7)) * 1024 + lt0 + (t & 63)];
    }

    // staging roles: wave stages part sp, rows (wv&1)*32 .. +32
    const int sp   = wv >> 1;
    const int kbs  = ((lane & 7) ^ (lane >> 3)) * 8;   // pre-swizzled src block

#define STAGEA(buf, hh)                                                      \
    do {                                                                     \
        const ushort* Kp = (sp ? KiB : KrB) + ((long)(hh) << 16);            \
        _Pragma("unroll")                                                    \
        for (int i = 0; i < 4; ++i) {                                        \
            const int krow = (wv & 1) * 32 + i * 8 + (lane >> 3);            \
            gl_lds16(Kp + (long)(sc * 64 + krow) * 64 + kbs,                 \
                     &stgK[buf][sp][(wv & 1) * 32 + i * 8][0]);              \
        }                                                                    \
    } while (0)

    f32x4 aR[4], aI[4];
#pragma unroll
    for (int i = 0; i < 4; ++i) {
        aR[i] = (f32x4){0.f, 0.f, 0.f, 0.f};
        aI[i] = (f32x4){0.f, 0.f, 0.f, 0.f};
    }

    const int kx  = (g ^ (col & 7)) * 8;
    const int kx2 = ((g + 4) ^ (col & 7)) * 8;

    STAGEA(0, 0);
    __syncthreads();

    for (int h = 0; h < 8; ++h) {
        const int buf = h & 1;
        if (h < 7) STAGEA(buf ^ 1, h + 1);

        // Q fragments for this head (row = col of wave's 16, k = g*8+e)
        const long qg = (((long)n * 1024 + l0 + col) * 8 + h) * 64 + g * 8;
        const f16x8 qr0 = cvt8(qr_g + qg), qr1 = cvt8(qr_g + qg + 32);
        const f16x8 qi0 = cvt8(qi_g + qg), qi1 = cvt8(qi_g + qg + 32);
        const f16x8 qn0 = negf(qi0), qn1 = negf(qi1);

        float rdR[4], rdI[4];
#pragma unroll
        for (int r = 0; r < 4; ++r) {
            rdR[r] = lrd[h][0][wv * 16 + 4 * g + r];
            rdI[r] = lrd[h][1][wv * 16 + 4 * g + r];
        }

#pragma unroll
        for (int sb = 0; sb < 4; ++sb) {
            const int row = sb * 16 + col;
            f16x8 kr0 = ld8(&stgK[buf][0][row][kx]);
            f16x8 kr1 = ld8(&stgK[buf][0][row][kx2]);
            f16x8 ki0 = ld8(&stgK[buf][1][row][kx]);
            f16x8 ki1 = ld8(&stgK[buf][1][row][kx2]);
            f32x4 a0 = (f32x4){0.f, 0.f, 0.f, 0.f};
            a0 = MFMA(qr0, kr0, a0); a0 = MFMA(qr1, kr1, a0);
            a0 = MFMA(qn0, ki0, a0); a0 = MFMA(qn1, ki1, a0);
            f32x4 a1 = (f32x4){0.f, 0.f, 0.f, 0.f};
            a1 = MFMA(qr0, ki0, a1); a1 = MFMA(qr1, ki1, a1);
            a1 = MFMA(qi0, kr0, a1); a1 = MFMA(qi1, kr1, a1);
#pragma unroll
            for (int r = 0; r < 4; ++r) {
                aR[sb][r] += exp2f(a0[r]) * rdR[r];
                aI[sb][r] += exp2f(a1[r]) * rdI[r];
            }
        }
        __syncthreads();
    }

    const long OFF_AR = 4194304;
    const long OFF_AI = 8388608;
#pragma unroll
    for (int sb = 0; sb < 4; ++sb) {
#pragma unroll
        for (int r = 0; r < 4; ++r) {
            const int l = l0 + 4 * g + r;
            const int s = sc * 64 + sb * 16 + col;
            const long ab = ((long)n * 1024 + l) * 1024 + s;
            out[OFF_AR + ab] = aR[sb][r] * 0.125f;
            out[OFF_AI + ab] = aI[sb][r] * 0.125f;
        }
    }
#undef STAGEA
}

extern "C" void kernel_launch(void* const* d_in, const int* in_sizes, int n_in,
                              void* d_out, int out_size, void* d_ws, size_t ws_size,
                              hipStream_t stream) {
    const float* qr = (const float*)d_in[0];
    const float* qi = (const float*)d_in[1];
    const float* kr = (const float*)d_in[2];
    const float* ki = (const float*)d_in[3];
    const float* vr = (const float*)d_in[4];
    const float* vi = (const float*)d_in[5];
    ushort* ws = (ushort*)d_ws;                              // 16 MB f16 K/V
    float* rdbuf = (float*)((char*)d_ws + (16ull << 20));    // 256 KB @ 16 MB
    float* out = (float*)d_out;

    hipLaunchKernelGGL(cvt_k, dim3(4096), dim3(256), 0, stream, kr, ki, ws);
    hipLaunchKernelGGL(cvt_v, dim3(1024), dim3(256), 0, stream, vr, vi, ws + (2l << 21));
    hipLaunchKernelGGL(attn_u, dim3(256), dim3(512), 0, stream, qr, qi, ws, rdbuf, out);
    hipLaunchKernelGGL(kern_a, dim3(1024), dim3(256), 0, stream, qr, qi, ws, rdbuf, out);
}